// Round 1
// baseline (3850.640 us; speedup 1.0000x reference)
//
#include <hip/hip_runtime.h>

#define NNODES 50000
#define EEDGES 800000
#define FIN 128
#define FH 128
#define FOUT 16
#define BN_EPS 1e-5f

// ---------------- scatter: agg[dst] += feat[src], cnt[dst] += 1 ----------------
// 32 threads per edge, each handles 4 contiguous floats (float4 load, 4 atomics).
__global__ void scatter_kernel(const float* __restrict__ feat,
                               const int* __restrict__ src,
                               const int* __restrict__ dst,
                               float* __restrict__ agg,
                               float* __restrict__ cnt,
                               int addCnt) {
    int tid = threadIdx.x;
    int e = blockIdx.x * 8 + (tid >> 5);
    if (e >= EEDGES) return;
    int s = src[e], d = dst[e];
    int fo = (tid & 31) << 2;
    const float4 v = *reinterpret_cast<const float4*>(feat + (size_t)s * FIN + fo);
    float* base = agg + (size_t)d * FIN + fo;
    atomicAdd(base + 0, v.x);
    atomicAdd(base + 1, v.y);
    atomicAdd(base + 2, v.z);
    atomicAdd(base + 3, v.w);
    if (addCnt && (tid & 31) == 0) atomicAdd(cnt + d, 1.0f);
}

// ---------------- lin1: h = (agg/cnt)@Wl^T + bl + x@Wr^T ----------------
// 256 threads/block = 2 nodes x 128 output features.
__global__ void lin1_kernel(const float* __restrict__ agg, const float* __restrict__ cnt,
                            const float* __restrict__ x,
                            const float* __restrict__ Wl, const float* __restrict__ bl,
                            const float* __restrict__ Wr,
                            float* __restrict__ h) {
    int tid = threadIdx.x;
    int i = blockIdx.x * 2 + (tid >> 7);
    int j = tid & 127;
    const float* ar = agg + (size_t)i * FIN;
    const float* xr = x + (size_t)i * FIN;
    float inv = 1.0f / fmaxf(cnt[i], 1.0f);
    const float* wl = Wl + j * FIN;
    const float* wr = Wr + j * FIN;
    float accl = 0.0f, accr = 0.0f;
    #pragma unroll 8
    for (int k = 0; k < FIN; ++k) {
        accl += ar[k] * wl[k];
        accr += xr[k] * wr[k];
    }
    h[(size_t)i * FH + j] = accl * inv + bl[j] + accr;
}

// ---------------- BN column reduction: partial sums + sumsq ----------------
__global__ void bn_reduce_kernel(const float* __restrict__ h,
                                 float* __restrict__ bnsum, float* __restrict__ bnsq,
                                 int rowsPerBlock) {
    int tid = threadIdx.x;
    int j = tid & 127;
    int half = tid >> 7; // 0 or 1
    int r0 = blockIdx.x * rowsPerBlock;
    int r1 = min(r0 + rowsPerBlock, NNODES);
    float s = 0.0f, sq = 0.0f;
    for (int r = r0 + half; r < r1; r += 2) {
        float v = h[(size_t)r * FH + j];
        s += v; sq += v * v;
    }
    __shared__ float sh[256];
    __shared__ float shq[256];
    sh[tid] = s; shq[tid] = sq;
    __syncthreads();
    if (half == 0) {
        atomicAdd(bnsum + j, sh[tid] + sh[tid + 128]);
        atomicAdd(bnsq + j, shq[tid] + shq[tid + 128]);
    }
}

// ---------------- BN apply + PReLU + residual (in-place on h) ----------------
__global__ void bn_apply_kernel(float* __restrict__ h, const float* __restrict__ x,
                                const float* __restrict__ gamma, const float* __restrict__ beta,
                                const float* __restrict__ aptr,
                                const float* __restrict__ bnsum, const float* __restrict__ bnsq) {
    int idx = blockIdx.x * blockDim.x + threadIdx.x;
    if (idx >= NNODES * FH) return;
    int j = idx & 127;
    const float invN = 1.0f / (float)NNODES;
    float mean = bnsum[j] * invN;
    float var = bnsq[j] * invN - mean * mean;
    float istd = rsqrtf(var + BN_EPS);
    float v = h[idx];
    v = gamma[j] * (v - mean) * istd + beta[j];
    float a = aptr[0];
    v = (v >= 0.0f) ? v : a * v;
    h[idx] = v + x[idx];
}

// ---------------- lin2 + log_softmax ----------------
// 16 threads per node (one per class); shuffle-reduce within 16-lane groups.
__global__ void lin2_kernel(const float* __restrict__ agg, const float* __restrict__ cnt,
                            const float* __restrict__ hres,
                            const float* __restrict__ Wl, const float* __restrict__ bl,
                            const float* __restrict__ Wr,
                            float* __restrict__ out) {
    int gid = blockIdx.x * blockDim.x + threadIdx.x;
    int i = gid >> 4;
    int j = gid & 15;
    if (i >= NNODES) return;
    const float* ar = agg + (size_t)i * FH;
    const float* hr = hres + (size_t)i * FH;
    float inv = 1.0f / fmaxf(cnt[i], 1.0f);
    const float* wl = Wl + j * FH;
    const float* wr = Wr + j * FH;
    float accl = 0.0f, accr = 0.0f;
    #pragma unroll 8
    for (int k = 0; k < FH; ++k) {
        accl += ar[k] * wl[k];
        accr += hr[k] * wr[k];
    }
    float v = accl * inv + bl[j] + accr;
    // log_softmax across the 16 lanes of this node
    float m = v;
    for (int s = 1; s < 16; s <<= 1) m = fmaxf(m, __shfl_xor(m, s, 16));
    float e = expf(v - m);
    float se = e;
    for (int s = 1; s < 16; s <<= 1) se += __shfl_xor(se, s, 16);
    out[(size_t)i * FOUT + j] = v - m - logf(se);
}

extern "C" void kernel_launch(void* const* d_in, const int* in_sizes, int n_in,
                              void* d_out, int out_size, void* d_ws, size_t ws_size,
                              hipStream_t stream) {
    const float* x    = (const float*)d_in[0];
    const int*   ei   = (const int*)d_in[1];
    const int*   src  = ei;
    const int*   dst  = ei + EEDGES;
    const float* Wl1  = (const float*)d_in[2];
    const float* bl1  = (const float*)d_in[3];
    const float* Wr1  = (const float*)d_in[4];
    const float* Wl2  = (const float*)d_in[5];
    const float* bl2  = (const float*)d_in[6];
    const float* Wr2  = (const float*)d_in[7];
    const float* gamma= (const float*)d_in[8];
    const float* beta = (const float*)d_in[9];
    const float* a    = (const float*)d_in[10];
    float* out = (float*)d_out;

    float* ws    = (float*)d_ws;
    float* agg   = ws;                 // 6,400,000 floats
    float* cnt   = ws + 6400000;       // 50,000
    float* bnsum = ws + 6450000;       // 128
    float* bnsq  = ws + 6450128;       // 128
    float* h     = ws + 6450256;       // 6,400,000

    // zero agg + cnt + bn partials in one shot
    hipMemsetAsync(agg, 0, (size_t)(6400000 + 50000 + 256) * sizeof(float), stream);

    scatter_kernel<<<EEDGES / 8, 256, 0, stream>>>(x, src, dst, agg, cnt, 1);
    lin1_kernel<<<NNODES / 2, 256, 0, stream>>>(agg, cnt, x, Wl1, bl1, Wr1, h);
    bn_reduce_kernel<<<512, 256, 0, stream>>>(h, bnsum, bnsq, (NNODES + 511) / 512);
    bn_apply_kernel<<<(NNODES * FH) / 256, 256, 0, stream>>>(h, x, gamma, beta, a, bnsum, bnsq);

    hipMemsetAsync(agg, 0, (size_t)6400000 * sizeof(float), stream);
    scatter_kernel<<<EEDGES / 8, 256, 0, stream>>>(h, src, dst, agg, cnt, 0);
    lin2_kernel<<<(NNODES * FOUT) / 256, 256, 0, stream>>>(agg, cnt, h, Wl2, bl2, Wr2, out);
}

// Round 2
// 1551.396 us; speedup vs baseline: 2.4820x; 2.4820x over previous
//
#include <hip/hip_runtime.h>

#define NNODES 50000
#define EEDGES 800000
#define FIN 128
#define FH 128
#define FOUT 16
#define BN_EPS 1e-5f

// ---------------- CSR build: degree count ----------------
__global__ void deg_kernel(const int* __restrict__ dst, int* __restrict__ deg) {
    int e = blockIdx.x * 256 + threadIdx.x;
    if (e < EEDGES) atomicAdd(&deg[dst[e]], 1);
}

// ---------------- single-workgroup exclusive scan over 50K degrees ----------------
__global__ void scan_kernel(const int* __restrict__ deg,
                            int* __restrict__ rowstart, int* __restrict__ writeptr) {
    __shared__ int sh[1024];
    int tid = threadIdx.x;
    int carry = 0;
    const int nchunk = (NNODES + 1023) / 1024;
    for (int c = 0; c < nchunk; ++c) {
        int idx = c * 1024 + tid;
        int v = (idx < NNODES) ? deg[idx] : 0;
        sh[tid] = v;
        __syncthreads();
        for (int off = 1; off < 1024; off <<= 1) {
            int t = (tid >= off) ? sh[tid - off] : 0;
            __syncthreads();
            sh[tid] += t;
            __syncthreads();
        }
        int excl = sh[tid] - v;   // exclusive prefix within chunk
        if (idx < NNODES) {
            rowstart[idx] = carry + excl;
            writeptr[idx] = carry + excl;
        }
        carry += sh[1023];
        __syncthreads();          // protect sh before next chunk overwrites
    }
    if (tid == 0) rowstart[NNODES] = carry;
}

// ---------------- bucket fill: srcSorted grouped by dst ----------------
__global__ void bucket_kernel(const int* __restrict__ src, const int* __restrict__ dst,
                              int* __restrict__ writeptr, int* __restrict__ srcSorted) {
    int e = blockIdx.x * 256 + threadIdx.x;
    if (e < EEDGES) {
        int p = atomicAdd(&writeptr[dst[e]], 1);
        srcSorted[p] = src[e];
    }
}

// ---------------- gather-aggregate: agg[i] = sum of feat[srcSorted[k]] ----------------
// 256 threads/block = 2 nodes x 128 features. Full overwrite (no zeroing needed).
__global__ void gather_agg_kernel(const float* __restrict__ feat,
                                  const int* __restrict__ rowstart,
                                  const int* __restrict__ srcSorted,
                                  float* __restrict__ agg) {
    int tid = threadIdx.x;
    int i = blockIdx.x * 2 + (tid >> 7);
    int j = tid & 127;
    int k0 = rowstart[i], k1 = rowstart[i + 1];
    float acc = 0.0f;
    for (int k = k0; k < k1; ++k) {
        acc += feat[(size_t)srcSorted[k] * FIN + j];
    }
    agg[(size_t)i * FIN + j] = acc;
}

// ---------------- lin1: h = (agg/deg)@Wl^T + bl + x@Wr^T ----------------
__global__ void lin1_kernel(const float* __restrict__ agg, const int* __restrict__ rowstart,
                            const float* __restrict__ x,
                            const float* __restrict__ Wl, const float* __restrict__ bl,
                            const float* __restrict__ Wr,
                            float* __restrict__ h) {
    int tid = threadIdx.x;
    int i = blockIdx.x * 2 + (tid >> 7);
    int j = tid & 127;
    const float* ar = agg + (size_t)i * FIN;
    const float* xr = x + (size_t)i * FIN;
    int d = rowstart[i + 1] - rowstart[i];
    float inv = 1.0f / (float)max(d, 1);
    const float* wl = Wl + j * FIN;
    const float* wr = Wr + j * FIN;
    float accl = 0.0f, accr = 0.0f;
    #pragma unroll 8
    for (int k = 0; k < FIN; ++k) {
        accl += ar[k] * wl[k];
        accr += xr[k] * wr[k];
    }
    h[(size_t)i * FH + j] = accl * inv + bl[j] + accr;
}

// ---------------- BN column reduction ----------------
__global__ void bn_reduce_kernel(const float* __restrict__ h,
                                 float* __restrict__ bnsum, float* __restrict__ bnsq,
                                 int rowsPerBlock) {
    int tid = threadIdx.x;
    int j = tid & 127;
    int half = tid >> 7;
    int r0 = blockIdx.x * rowsPerBlock;
    int r1 = min(r0 + rowsPerBlock, NNODES);
    float s = 0.0f, sq = 0.0f;
    for (int r = r0 + half; r < r1; r += 2) {
        float v = h[(size_t)r * FH + j];
        s += v; sq += v * v;
    }
    __shared__ float sh[256];
    __shared__ float shq[256];
    sh[tid] = s; shq[tid] = sq;
    __syncthreads();
    if (half == 0) {
        atomicAdd(bnsum + j, sh[tid] + sh[tid + 128]);
        atomicAdd(bnsq + j, shq[tid] + shq[tid + 128]);
    }
}

// ---------------- BN apply + PReLU + residual (in-place) ----------------
__global__ void bn_apply_kernel(float* __restrict__ h, const float* __restrict__ x,
                                const float* __restrict__ gamma, const float* __restrict__ beta,
                                const float* __restrict__ aptr,
                                const float* __restrict__ bnsum, const float* __restrict__ bnsq) {
    int idx = blockIdx.x * blockDim.x + threadIdx.x;
    if (idx >= NNODES * FH) return;
    int j = idx & 127;
    const float invN = 1.0f / (float)NNODES;
    float mean = bnsum[j] * invN;
    float var = bnsq[j] * invN - mean * mean;
    float istd = rsqrtf(var + BN_EPS);
    float v = h[idx];
    v = gamma[j] * (v - mean) * istd + beta[j];
    float a = aptr[0];
    v = (v >= 0.0f) ? v : a * v;
    h[idx] = v + x[idx];
}

// ---------------- lin2 + log_softmax ----------------
__global__ void lin2_kernel(const float* __restrict__ agg, const int* __restrict__ rowstart,
                            const float* __restrict__ hres,
                            const float* __restrict__ Wl, const float* __restrict__ bl,
                            const float* __restrict__ Wr,
                            float* __restrict__ out) {
    int gid = blockIdx.x * blockDim.x + threadIdx.x;
    int i = gid >> 4;
    int j = gid & 15;
    if (i >= NNODES) return;
    const float* ar = agg + (size_t)i * FH;
    const float* hr = hres + (size_t)i * FH;
    int d = rowstart[i + 1] - rowstart[i];
    float inv = 1.0f / (float)max(d, 1);
    const float* wl = Wl + j * FH;
    const float* wr = Wr + j * FH;
    float accl = 0.0f, accr = 0.0f;
    #pragma unroll 8
    for (int k = 0; k < FH; ++k) {
        accl += ar[k] * wl[k];
        accr += hr[k] * wr[k];
    }
    float v = accl * inv + bl[j] + accr;
    float m = v;
    for (int s = 1; s < 16; s <<= 1) m = fmaxf(m, __shfl_xor(m, s, 16));
    float e = expf(v - m);
    float se = e;
    for (int s = 1; s < 16; s <<= 1) se += __shfl_xor(se, s, 16);
    out[(size_t)i * FOUT + j] = v - m - logf(se);
}

extern "C" void kernel_launch(void* const* d_in, const int* in_sizes, int n_in,
                              void* d_out, int out_size, void* d_ws, size_t ws_size,
                              hipStream_t stream) {
    const float* x    = (const float*)d_in[0];
    const int*   ei   = (const int*)d_in[1];
    const int*   src  = ei;
    const int*   dst  = ei + EEDGES;
    const float* Wl1  = (const float*)d_in[2];
    const float* bl1  = (const float*)d_in[3];
    const float* Wr1  = (const float*)d_in[4];
    const float* Wl2  = (const float*)d_in[5];
    const float* bl2  = (const float*)d_in[6];
    const float* Wr2  = (const float*)d_in[7];
    const float* gamma= (const float*)d_in[8];
    const float* beta = (const float*)d_in[9];
    const float* a    = (const float*)d_in[10];
    float* out = (float*)d_out;

    float* ws    = (float*)d_ws;
    float* agg   = ws;                        // 6,400,000 f
    float* h     = ws + 6400000;              // 6,400,000 f
    float* bnsum = ws + 12800000;             // 128 f
    float* bnsq  = ws + 12800128;             // 128 f
    int* deg       = (int*)(ws + 12800256);   // 50,000 i
    int* rowstart  = deg + 50000;             // 50,001 i
    int* writeptr  = rowstart + 50004;        // 50,000 i
    int* srcSorted = writeptr + 50000;        // 800,000 i

    // zero bn partials + degree counters (contiguous region)
    hipMemsetAsync(bnsum, 0, (size_t)(256 + 50000) * sizeof(float), stream);

    // CSR build (once; reused by both layers)
    deg_kernel<<<(EEDGES + 255) / 256, 256, 0, stream>>>(dst, deg);
    scan_kernel<<<1, 1024, 0, stream>>>(deg, rowstart, writeptr);
    bucket_kernel<<<(EEDGES + 255) / 256, 256, 0, stream>>>(src, dst, writeptr, srcSorted);

    // layer 1
    gather_agg_kernel<<<NNODES / 2, 256, 0, stream>>>(x, rowstart, srcSorted, agg);
    lin1_kernel<<<NNODES / 2, 256, 0, stream>>>(agg, rowstart, x, Wl1, bl1, Wr1, h);
    bn_reduce_kernel<<<512, 256, 0, stream>>>(h, bnsum, bnsq, (NNODES + 511) / 512);
    bn_apply_kernel<<<(NNODES * FH) / 256, 256, 0, stream>>>(h, x, gamma, beta, a, bnsum, bnsq);

    // layer 2
    gather_agg_kernel<<<NNODES / 2, 256, 0, stream>>>(h, rowstart, srcSorted, agg);
    lin2_kernel<<<(NNODES * FOUT) / 256, 256, 0, stream>>>(agg, rowstart, h, Wl2, bl2, Wr2, out);
}

// Round 3
// 382.439 us; speedup vs baseline: 10.0686x; 4.0566x over previous
//
#include <hip/hip_runtime.h>

#define NNODES 50000
#define EEDGES 800000
#define FIN 128
#define FH 128
#define FOUT 16
#define BN_EPS 1e-5f

typedef short bf16x8 __attribute__((ext_vector_type(8)));
typedef float f32x4 __attribute__((ext_vector_type(4)));

__device__ inline unsigned short tobf16(float f) {
    unsigned int u = __float_as_uint(f);
    u += 0x7fffu + ((u >> 16) & 1u);   // RNE
    return (unsigned short)(u >> 16);
}
__device__ inline float frombf16(unsigned short h) {
    return __uint_as_float(((unsigned int)h) << 16);
}

// ---------------- pack: xb = bf16(x); wbuf = bf16(Wl1|Wr1|Wl2|Wr2) ----------------
__global__ void pack_kernel(const float* __restrict__ x,
                            const float* __restrict__ Wl1, const float* __restrict__ Wr1,
                            const float* __restrict__ Wl2, const float* __restrict__ Wr2,
                            unsigned short* __restrict__ xb, unsigned short* __restrict__ wb) {
    int idx = blockIdx.x * 256 + threadIdx.x;
    if (idx < NNODES * FIN) {
        xb[idx] = tobf16(x[idx]);
    } else if (idx < NNODES * FIN + 36864) {
        int w = idx - NNODES * FIN;
        float v;
        if (w < 16384) v = Wl1[w];
        else if (w < 32768) v = Wr1[w - 16384];
        else if (w < 34816) v = Wl2[w - 32768];
        else v = Wr2[w - 34816];
        wb[w] = tobf16(v);
    }
}

// ---------------- CSR build ----------------
__global__ void deg_kernel(const int* __restrict__ dst, int* __restrict__ deg) {
    int e = blockIdx.x * 256 + threadIdx.x;
    if (e < EEDGES) atomicAdd(&deg[dst[e]], 1);
}

// single WG: per-thread sequential + one block scan
__global__ void scan_kernel(const int* __restrict__ deg,
                            int* __restrict__ rowstart, int* __restrict__ writeptr) {
    __shared__ int tot[1024];
    int tid = threadIdx.x;
    const int NPT = 49;  // 1024*49 = 50176 >= NNODES
    int base = tid * NPT;
    int s = 0;
    for (int i = 0; i < NPT; ++i) {
        int idx = base + i;
        s += (idx < NNODES) ? deg[idx] : 0;
    }
    tot[tid] = s;
    __syncthreads();
    for (int off = 1; off < 1024; off <<= 1) {
        int t = (tid >= off) ? tot[tid - off] : 0;
        __syncthreads();
        tot[tid] += t;
        __syncthreads();
    }
    int run = tot[tid] - s;  // exclusive prefix of this thread's chunk
    for (int i = 0; i < NPT; ++i) {
        int idx = base + i;
        if (idx < NNODES) {
            rowstart[idx] = run;
            writeptr[idx] = run;
            run += deg[idx];
        }
    }
    if (tid == 1023) rowstart[NNODES] = run;
}

__global__ void bucket_kernel(const int* __restrict__ src, const int* __restrict__ dst,
                              int* __restrict__ writeptr, int* __restrict__ srcSorted) {
    int e = blockIdx.x * 256 + threadIdx.x;
    if (e < EEDGES) {
        int p = atomicAdd(&writeptr[dst[e]], 1);
        srcSorted[p] = src[e];
    }
}

// ---------------- gather (bf16 in, bf16 scaled-by-1/deg out) ----------------
// 1 wave per node; each lane handles 2 features via uint loads (full 256B row/wave).
__global__ void gather_bf16(const unsigned short* __restrict__ feat,
                            const int* __restrict__ rowstart,
                            const int* __restrict__ srcSorted,
                            unsigned short* __restrict__ aggout) {
    int tid = threadIdx.x;
    int i = blockIdx.x * 4 + (tid >> 6);
    int j = tid & 63;
    const unsigned int* fp = (const unsigned int*)feat;
    int k0 = rowstart[i], k1 = rowstart[i + 1];
    float a0 = 0.0f, a1 = 0.0f;
    int k = k0;
    for (; k + 4 <= k1; k += 4) {
        int s0 = srcSorted[k], s1 = srcSorted[k + 1], s2 = srcSorted[k + 2], s3 = srcSorted[k + 3];
        unsigned int u0 = fp[(size_t)s0 * 64 + j];
        unsigned int u1 = fp[(size_t)s1 * 64 + j];
        unsigned int u2 = fp[(size_t)s2 * 64 + j];
        unsigned int u3 = fp[(size_t)s3 * 64 + j];
        a0 += __uint_as_float(u0 << 16) + __uint_as_float(u1 << 16)
            + __uint_as_float(u2 << 16) + __uint_as_float(u3 << 16);
        a1 += __uint_as_float(u0 & 0xffff0000u) + __uint_as_float(u1 & 0xffff0000u)
            + __uint_as_float(u2 & 0xffff0000u) + __uint_as_float(u3 & 0xffff0000u);
    }
    for (; k < k1; ++k) {
        unsigned int u = fp[(size_t)srcSorted[k] * 64 + j];
        a0 += __uint_as_float(u << 16);
        a1 += __uint_as_float(u & 0xffff0000u);
    }
    float inv = 1.0f / (float)max(k1 - k0, 1);
    unsigned int pk = (unsigned int)tobf16(a0 * inv) | ((unsigned int)tobf16(a1 * inv) << 16);
    ((unsigned int*)aggout)[(size_t)i * 64 + j] = pk;
}

// ---------------- lin1 MFMA: hb = bf16(aggb@Wl^T + xb@Wr^T + bl) ----------------
// block 256 = 4 waves; wave handles 16 rows x 128 cols. 64 MFMA/wave.
__global__ void lin1_mfma(const unsigned short* __restrict__ aggb,
                          const unsigned short* __restrict__ xb,
                          const unsigned short* __restrict__ wl,
                          const unsigned short* __restrict__ wr,
                          const float* __restrict__ bias,
                          unsigned short* __restrict__ hb) {
    int wave = threadIdx.x >> 6;
    int lane = threadIdx.x & 63;
    int row0 = blockIdx.x * 64 + wave * 16;
    int lrow = lane & 15;
    int kg = lane >> 4;
    int arow = min(row0 + lrow, NNODES - 1);
    f32x4 acc[8] = {};
    #pragma unroll
    for (int ks = 0; ks < 4; ++ks) {
        bf16x8 a = *(const bf16x8*)(aggb + (size_t)arow * 128 + ks * 32 + kg * 8);
        #pragma unroll
        for (int nf = 0; nf < 8; ++nf) {
            bf16x8 b = *(const bf16x8*)(wl + (size_t)(nf * 16 + lrow) * 128 + ks * 32 + kg * 8);
            acc[nf] = __builtin_amdgcn_mfma_f32_16x16x32_bf16(a, b, acc[nf], 0, 0, 0);
        }
    }
    #pragma unroll
    for (int ks = 0; ks < 4; ++ks) {
        bf16x8 a = *(const bf16x8*)(xb + (size_t)arow * 128 + ks * 32 + kg * 8);
        #pragma unroll
        for (int nf = 0; nf < 8; ++nf) {
            bf16x8 b = *(const bf16x8*)(wr + (size_t)(nf * 16 + lrow) * 128 + ks * 32 + kg * 8);
            acc[nf] = __builtin_amdgcn_mfma_f32_16x16x32_bf16(a, b, acc[nf], 0, 0, 0);
        }
    }
    // C/D: col = nf*16 + lrow, row = row0 + kg*4 + r
    #pragma unroll
    for (int nf = 0; nf < 8; ++nf) {
        float b = bias[nf * 16 + lrow];
        #pragma unroll
        for (int r = 0; r < 4; ++r) {
            int row = row0 + kg * 4 + r;
            if (row < NNODES)
                hb[(size_t)row * 128 + nf * 16 + lrow] = tobf16(acc[nf][r] + b);
        }
    }
}

// ---------------- BN column reduction (reads bf16 h) ----------------
__global__ void bn_reduce_kernel(const unsigned short* __restrict__ hb,
                                 float* __restrict__ bnsum, float* __restrict__ bnsq,
                                 int rowsPerBlock) {
    int tid = threadIdx.x;
    int j = tid & 127;
    int half = tid >> 7;
    int r0 = blockIdx.x * rowsPerBlock;
    int r1 = min(r0 + rowsPerBlock, NNODES);
    float s = 0.0f, sq = 0.0f;
    for (int r = r0 + half; r < r1; r += 2) {
        float v = frombf16(hb[(size_t)r * FH + j]);
        s += v; sq += v * v;
    }
    __shared__ float sh[256];
    __shared__ float shq[256];
    sh[tid] = s; shq[tid] = sq;
    __syncthreads();
    if (half == 0) {
        atomicAdd(bnsum + j, sh[tid] + sh[tid + 128]);
        atomicAdd(bnsq + j, shq[tid] + shq[tid + 128]);
    }
}

// ---------------- BN apply + PReLU + residual, in place on hb ----------------
__global__ void bn_apply_kernel(unsigned short* __restrict__ hb, const float* __restrict__ x,
                                const float* __restrict__ gamma, const float* __restrict__ beta,
                                const float* __restrict__ aptr,
                                const float* __restrict__ bnsum, const float* __restrict__ bnsq) {
    int idx = blockIdx.x * 256 + threadIdx.x;
    if (idx >= NNODES * FH) return;
    int j = idx & 127;
    const float invN = 1.0f / (float)NNODES;
    float mean = bnsum[j] * invN;
    float var = bnsq[j] * invN - mean * mean;
    float istd = rsqrtf(var + BN_EPS);
    float v = frombf16(hb[idx]);
    v = gamma[j] * (v - mean) * istd + beta[j];
    float a = aptr[0];
    v = (v >= 0.0f) ? v : a * v;
    hb[idx] = tobf16(v + x[idx]);
}

// ---------------- lin2 MFMA + log_softmax ----------------
// wave handles 16 rows x 16 cols (one fragment), 8 MFMA; softmax across 16 lanes.
__global__ void lin2_mfma(const unsigned short* __restrict__ aggb,
                          const unsigned short* __restrict__ hb,
                          const unsigned short* __restrict__ wl,
                          const unsigned short* __restrict__ wr,
                          const float* __restrict__ bias,
                          float* __restrict__ out) {
    int wave = threadIdx.x >> 6;
    int lane = threadIdx.x & 63;
    int row0 = blockIdx.x * 64 + wave * 16;
    int lrow = lane & 15;
    int kg = lane >> 4;
    int arow = min(row0 + lrow, NNODES - 1);
    f32x4 acc = {};
    #pragma unroll
    for (int ks = 0; ks < 4; ++ks) {
        bf16x8 a = *(const bf16x8*)(aggb + (size_t)arow * 128 + ks * 32 + kg * 8);
        bf16x8 b = *(const bf16x8*)(wl + (size_t)lrow * 128 + ks * 32 + kg * 8);
        acc = __builtin_amdgcn_mfma_f32_16x16x32_bf16(a, b, acc, 0, 0, 0);
    }
    #pragma unroll
    for (int ks = 0; ks < 4; ++ks) {
        bf16x8 a = *(const bf16x8*)(hb + (size_t)arow * 128 + ks * 32 + kg * 8);
        bf16x8 b = *(const bf16x8*)(wr + (size_t)lrow * 128 + ks * 32 + kg * 8);
        acc = __builtin_amdgcn_mfma_f32_16x16x32_bf16(a, b, acc, 0, 0, 0);
    }
    float bl = bias[lrow];
    #pragma unroll
    for (int r = 0; r < 4; ++r) {
        float v = acc[r] + bl;
        float m = v;
        for (int s = 1; s < 16; s <<= 1) m = fmaxf(m, __shfl_xor(m, s, 16));
        float e = expf(v - m);
        float se = e;
        for (int s = 1; s < 16; s <<= 1) se += __shfl_xor(se, s, 16);
        int row = row0 + kg * 4 + r;
        if (row < NNODES)
            out[(size_t)row * FOUT + lrow] = v - m - logf(se);
    }
}

extern "C" void kernel_launch(void* const* d_in, const int* in_sizes, int n_in,
                              void* d_out, int out_size, void* d_ws, size_t ws_size,
                              hipStream_t stream) {
    const float* x    = (const float*)d_in[0];
    const int*   ei   = (const int*)d_in[1];
    const int*   src  = ei;
    const int*   dst  = ei + EEDGES;
    const float* Wl1  = (const float*)d_in[2];
    const float* bl1  = (const float*)d_in[3];
    const float* Wr1  = (const float*)d_in[4];
    const float* Wl2  = (const float*)d_in[5];
    const float* bl2  = (const float*)d_in[6];
    const float* Wr2  = (const float*)d_in[7];
    const float* gamma= (const float*)d_in[8];
    const float* beta = (const float*)d_in[9];
    const float* a    = (const float*)d_in[10];
    float* out = (float*)d_out;

    char* W = (char*)d_ws;
    unsigned short* aggb = (unsigned short*)(W + 0);          // 12,800,000 B
    unsigned short* xb   = (unsigned short*)(W + 12800000);   // 12,800,000 B
    unsigned short* hb   = (unsigned short*)(W + 25600000);   // 12,800,000 B
    unsigned short* wb   = (unsigned short*)(W + 38400000);   // 73,728 B
    float* bnsum   = (float*)(W + 38473728);                  // 512 B
    float* bnsq    = (float*)(W + 38474240);                  // 512 B
    int* deg       = (int*)(W + 38474752);                    // 200,000 B
    int* rowstart  = (int*)(W + 38674752);                    // 200,016 B
    int* writeptr  = (int*)(W + 38874768);                    // 200,000 B
    int* srcSorted = (int*)(W + 39074768);                    // 3,200,000 B

    unsigned short* wl1b = wb;
    unsigned short* wr1b = wb + 16384;
    unsigned short* wl2b = wb + 32768;
    unsigned short* wr2b = wb + 34816;

    // zero bnsum+bnsq+deg (contiguous)
    hipMemsetAsync(bnsum, 0, (size_t)(1024 + 200000), stream);

    pack_kernel<<<25145, 256, 0, stream>>>(x, Wl1, Wr1, Wl2, Wr2, xb, wb);

    deg_kernel<<<EEDGES / 256, 256, 0, stream>>>(dst, deg);
    scan_kernel<<<1, 1024, 0, stream>>>(deg, rowstart, writeptr);
    bucket_kernel<<<EEDGES / 256, 256, 0, stream>>>(src, dst, writeptr, srcSorted);

    // layer 1
    gather_bf16<<<NNODES / 4, 256, 0, stream>>>(xb, rowstart, srcSorted, aggb);
    lin1_mfma<<<(NNODES + 63) / 64, 256, 0, stream>>>(aggb, xb, wl1b, wr1b, bl1, hb);
    bn_reduce_kernel<<<512, 256, 0, stream>>>(hb, bnsum, bnsq, (NNODES + 511) / 512);
    bn_apply_kernel<<<(NNODES * FH) / 256, 256, 0, stream>>>(hb, x, gamma, beta, a, bnsum, bnsq);

    // layer 2
    gather_bf16<<<NNODES / 4, 256, 0, stream>>>(hb, rowstart, srcSorted, aggb);
    lin2_mfma<<<(NNODES + 63) / 64, 256, 0, stream>>>(aggb, hb, wl2b, wr2b, bl2, out);
}

// Round 4
// 267.879 us; speedup vs baseline: 14.3746x; 1.4277x over previous
//
#include <hip/hip_runtime.h>

#define NNODES 50000
#define EEDGES 800000
#define FIN 128
#define FH 128
#define FOUT 16
#define BN_EPS 1e-5f
#define NB 196  // ceil(50000/256)

typedef short bf16x8 __attribute__((ext_vector_type(8)));
typedef float f32x4 __attribute__((ext_vector_type(4)));

__device__ inline unsigned short tobf16(float f) {
    unsigned int u = __float_as_uint(f);
    u += 0x7fffu + ((u >> 16) & 1u);   // RNE
    return (unsigned short)(u >> 16);
}
__device__ inline float frombf16(unsigned short h) {
    return __uint_as_float(((unsigned int)h) << 16);
}

// ---------------- pack: xb = bf16(x); wbuf = bf16(Wl1|Wr1|Wl2|Wr2) ----------------
__global__ void pack_kernel(const float* __restrict__ x,
                            const float* __restrict__ Wl1, const float* __restrict__ Wr1,
                            const float* __restrict__ Wl2, const float* __restrict__ Wr2,
                            unsigned short* __restrict__ xb, unsigned short* __restrict__ wb) {
    int idx = blockIdx.x * 256 + threadIdx.x;
    if (idx < NNODES * FIN) {
        xb[idx] = tobf16(x[idx]);
    } else if (idx < NNODES * FIN + 36864) {
        int w = idx - NNODES * FIN;
        float v;
        if (w < 16384) v = Wl1[w];
        else if (w < 32768) v = Wr1[w - 16384];
        else if (w < 34816) v = Wl2[w - 32768];
        else v = Wr2[w - 34816];
        wb[w] = tobf16(v);
    }
}

// ---------------- CSR build ----------------
__global__ void deg_kernel(const int* __restrict__ dst, int* __restrict__ deg) {
    int e = blockIdx.x * 256 + threadIdx.x;
    if (e < EEDGES) atomicAdd(&deg[dst[e]], 1);
}

// phase 1: per-block degree sums
__global__ void blocksum_kernel(const int* __restrict__ deg, int* __restrict__ blockSums) {
    int idx = blockIdx.x * 256 + threadIdx.x;
    int v = (idx < NNODES) ? deg[idx] : 0;
    for (int off = 32; off; off >>= 1) v += __shfl_down(v, off, 64);
    __shared__ int sh[4];
    if ((threadIdx.x & 63) == 0) sh[threadIdx.x >> 6] = v;
    __syncthreads();
    if (threadIdx.x == 0) blockSums[blockIdx.x] = sh[0] + sh[1] + sh[2] + sh[3];
}

// phase 2: single block scans the 196 block sums -> exclusive offsets
__global__ void scanblocks_kernel(const int* __restrict__ blockSums, int* __restrict__ blockOff) {
    __shared__ int sh[256];
    int tid = threadIdx.x;
    int v = (tid < NB) ? blockSums[tid] : 0;
    sh[tid] = v;
    __syncthreads();
    for (int off = 1; off < 256; off <<= 1) {
        int t = (tid >= off) ? sh[tid - off] : 0;
        __syncthreads();
        sh[tid] += t;
        __syncthreads();
    }
    if (tid < NB) blockOff[tid] = sh[tid] - v;
}

// phase 3: per-block exclusive scan + offset -> rowstart/writeptr (coalesced)
__global__ void blockscan_kernel(const int* __restrict__ deg, const int* __restrict__ blockOff,
                                 int* __restrict__ rowstart, int* __restrict__ writeptr) {
    __shared__ int sh[256];
    int tid = threadIdx.x;
    int idx = blockIdx.x * 256 + tid;
    int v = (idx < NNODES) ? deg[idx] : 0;
    sh[tid] = v;
    __syncthreads();
    for (int off = 1; off < 256; off <<= 1) {
        int t = (tid >= off) ? sh[tid - off] : 0;
        __syncthreads();
        sh[tid] += t;
        __syncthreads();
    }
    int r = blockOff[blockIdx.x] + sh[tid] - v;
    if (idx < NNODES) { rowstart[idx] = r; writeptr[idx] = r; }
    if (idx == 0) rowstart[NNODES] = EEDGES;  // every edge's dst is in range
}

__global__ void bucket_kernel(const int* __restrict__ src, const int* __restrict__ dst,
                              int* __restrict__ writeptr, int* __restrict__ srcSorted) {
    int e = blockIdx.x * 256 + threadIdx.x;
    if (e < EEDGES) {
        int p = atomicAdd(&writeptr[dst[e]], 1);
        srcSorted[p] = src[e];
    }
}

// ---------------- gather (bf16 in, bf16 scaled-by-1/deg out) ----------------
// 1 wave per node; each lane handles 2 features via uint loads (full 256B row/wave).
__global__ void gather_bf16(const unsigned short* __restrict__ feat,
                            const int* __restrict__ rowstart,
                            const int* __restrict__ srcSorted,
                            unsigned short* __restrict__ aggout) {
    int tid = threadIdx.x;
    int i = blockIdx.x * 4 + (tid >> 6);
    int j = tid & 63;
    const unsigned int* fp = (const unsigned int*)feat;
    int k0 = rowstart[i], k1 = rowstart[i + 1];
    float a0 = 0.0f, a1 = 0.0f;
    int k = k0;
    for (; k + 4 <= k1; k += 4) {
        int s0 = srcSorted[k], s1 = srcSorted[k + 1], s2 = srcSorted[k + 2], s3 = srcSorted[k + 3];
        unsigned int u0 = fp[(size_t)s0 * 64 + j];
        unsigned int u1 = fp[(size_t)s1 * 64 + j];
        unsigned int u2 = fp[(size_t)s2 * 64 + j];
        unsigned int u3 = fp[(size_t)s3 * 64 + j];
        a0 += __uint_as_float(u0 << 16) + __uint_as_float(u1 << 16)
            + __uint_as_float(u2 << 16) + __uint_as_float(u3 << 16);
        a1 += __uint_as_float(u0 & 0xffff0000u) + __uint_as_float(u1 & 0xffff0000u)
            + __uint_as_float(u2 & 0xffff0000u) + __uint_as_float(u3 & 0xffff0000u);
    }
    for (; k < k1; ++k) {
        unsigned int u = fp[(size_t)srcSorted[k] * 64 + j];
        a0 += __uint_as_float(u << 16);
        a1 += __uint_as_float(u & 0xffff0000u);
    }
    float inv = 1.0f / (float)max(k1 - k0, 1);
    unsigned int pk = (unsigned int)tobf16(a0 * inv) | ((unsigned int)tobf16(a1 * inv) << 16);
    ((unsigned int*)aggout)[(size_t)i * 64 + j] = pk;
}

// ---------------- lin1 MFMA: hb = bf16(aggb@Wl^T + xb@Wr^T + bl) ----------------
__global__ void lin1_mfma(const unsigned short* __restrict__ aggb,
                          const unsigned short* __restrict__ xb,
                          const unsigned short* __restrict__ wl,
                          const unsigned short* __restrict__ wr,
                          const float* __restrict__ bias,
                          unsigned short* __restrict__ hb) {
    int wave = threadIdx.x >> 6;
    int lane = threadIdx.x & 63;
    int row0 = blockIdx.x * 64 + wave * 16;
    int lrow = lane & 15;
    int kg = lane >> 4;
    int arow = min(row0 + lrow, NNODES - 1);
    f32x4 acc[8] = {};
    #pragma unroll
    for (int ks = 0; ks < 4; ++ks) {
        bf16x8 a = *(const bf16x8*)(aggb + (size_t)arow * 128 + ks * 32 + kg * 8);
        #pragma unroll
        for (int nf = 0; nf < 8; ++nf) {
            bf16x8 b = *(const bf16x8*)(wl + (size_t)(nf * 16 + lrow) * 128 + ks * 32 + kg * 8);
            acc[nf] = __builtin_amdgcn_mfma_f32_16x16x32_bf16(a, b, acc[nf], 0, 0, 0);
        }
    }
    #pragma unroll
    for (int ks = 0; ks < 4; ++ks) {
        bf16x8 a = *(const bf16x8*)(xb + (size_t)arow * 128 + ks * 32 + kg * 8);
        #pragma unroll
        for (int nf = 0; nf < 8; ++nf) {
            bf16x8 b = *(const bf16x8*)(wr + (size_t)(nf * 16 + lrow) * 128 + ks * 32 + kg * 8);
            acc[nf] = __builtin_amdgcn_mfma_f32_16x16x32_bf16(a, b, acc[nf], 0, 0, 0);
        }
    }
    #pragma unroll
    for (int nf = 0; nf < 8; ++nf) {
        float b = bias[nf * 16 + lrow];
        #pragma unroll
        for (int r = 0; r < 4; ++r) {
            int row = row0 + kg * 4 + r;
            if (row < NNODES)
                hb[(size_t)row * 128 + nf * 16 + lrow] = tobf16(acc[nf][r] + b);
        }
    }
}

// ---------------- BN column reduction (reads bf16 h) ----------------
__global__ void bn_reduce_kernel(const unsigned short* __restrict__ hb,
                                 float* __restrict__ bnsum, float* __restrict__ bnsq,
                                 int rowsPerBlock) {
    int tid = threadIdx.x;
    int j = tid & 127;
    int half = tid >> 7;
    int r0 = blockIdx.x * rowsPerBlock;
    int r1 = min(r0 + rowsPerBlock, NNODES);
    float s = 0.0f, sq = 0.0f;
    for (int r = r0 + half; r < r1; r += 2) {
        float v = frombf16(hb[(size_t)r * FH + j]);
        s += v; sq += v * v;
    }
    __shared__ float sh[256];
    __shared__ float shq[256];
    sh[tid] = s; shq[tid] = sq;
    __syncthreads();
    if (half == 0) {
        atomicAdd(bnsum + j, sh[tid] + sh[tid + 128]);
        atomicAdd(bnsq + j, shq[tid] + shq[tid + 128]);
    }
}

// ---------------- BN apply + PReLU + residual, in place on hb ----------------
__global__ void bn_apply_kernel(unsigned short* __restrict__ hb, const float* __restrict__ x,
                                const float* __restrict__ gamma, const float* __restrict__ beta,
                                const float* __restrict__ aptr,
                                const float* __restrict__ bnsum, const float* __restrict__ bnsq) {
    int idx = blockIdx.x * 256 + threadIdx.x;
    if (idx >= NNODES * FH) return;
    int j = idx & 127;
    const float invN = 1.0f / (float)NNODES;
    float mean = bnsum[j] * invN;
    float var = bnsq[j] * invN - mean * mean;
    float istd = rsqrtf(var + BN_EPS);
    float v = frombf16(hb[idx]);
    v = gamma[j] * (v - mean) * istd + beta[j];
    float a = aptr[0];
    v = (v >= 0.0f) ? v : a * v;
    hb[idx] = tobf16(v + x[idx]);
}

// ---------------- lin2 MFMA + log_softmax ----------------
__global__ void lin2_mfma(const unsigned short* __restrict__ aggb,
                          const unsigned short* __restrict__ hb,
                          const unsigned short* __restrict__ wl,
                          const unsigned short* __restrict__ wr,
                          const float* __restrict__ bias,
                          float* __restrict__ out) {
    int wave = threadIdx.x >> 6;
    int lane = threadIdx.x & 63;
    int row0 = blockIdx.x * 64 + wave * 16;
    int lrow = lane & 15;
    int kg = lane >> 4;
    int arow = min(row0 + lrow, NNODES - 1);
    f32x4 acc = {};
    #pragma unroll
    for (int ks = 0; ks < 4; ++ks) {
        bf16x8 a = *(const bf16x8*)(aggb + (size_t)arow * 128 + ks * 32 + kg * 8);
        bf16x8 b = *(const bf16x8*)(wl + (size_t)lrow * 128 + ks * 32 + kg * 8);
        acc = __builtin_amdgcn_mfma_f32_16x16x32_bf16(a, b, acc, 0, 0, 0);
    }
    #pragma unroll
    for (int ks = 0; ks < 4; ++ks) {
        bf16x8 a = *(const bf16x8*)(hb + (size_t)arow * 128 + ks * 32 + kg * 8);
        bf16x8 b = *(const bf16x8*)(wr + (size_t)lrow * 128 + ks * 32 + kg * 8);
        acc = __builtin_amdgcn_mfma_f32_16x16x32_bf16(a, b, acc, 0, 0, 0);
    }
    float bl = bias[lrow];
    #pragma unroll
    for (int r = 0; r < 4; ++r) {
        float v = acc[r] + bl;
        float m = v;
        for (int s = 1; s < 16; s <<= 1) m = fmaxf(m, __shfl_xor(m, s, 16));
        float e = expf(v - m);
        float se = e;
        for (int s = 1; s < 16; s <<= 1) se += __shfl_xor(se, s, 16);
        int row = row0 + kg * 4 + r;
        if (row < NNODES)
            out[(size_t)row * FOUT + lrow] = v - m - logf(se);
    }
}

extern "C" void kernel_launch(void* const* d_in, const int* in_sizes, int n_in,
                              void* d_out, int out_size, void* d_ws, size_t ws_size,
                              hipStream_t stream) {
    const float* x    = (const float*)d_in[0];
    const int*   ei   = (const int*)d_in[1];
    const int*   src  = ei;
    const int*   dst  = ei + EEDGES;
    const float* Wl1  = (const float*)d_in[2];
    const float* bl1  = (const float*)d_in[3];
    const float* Wr1  = (const float*)d_in[4];
    const float* Wl2  = (const float*)d_in[5];
    const float* bl2  = (const float*)d_in[6];
    const float* Wr2  = (const float*)d_in[7];
    const float* gamma= (const float*)d_in[8];
    const float* beta = (const float*)d_in[9];
    const float* a    = (const float*)d_in[10];
    float* out = (float*)d_out;

    char* W = (char*)d_ws;
    unsigned short* aggb = (unsigned short*)(W + 0);          // 12,800,000 B
    unsigned short* xb   = (unsigned short*)(W + 12800000);   // 12,800,000 B
    unsigned short* hb   = (unsigned short*)(W + 25600000);   // 12,800,000 B
    unsigned short* wb   = (unsigned short*)(W + 38400000);   // 73,728 B
    float* bnsum   = (float*)(W + 38473728);                  // 512 B
    float* bnsq    = (float*)(W + 38474240);                  // 512 B
    int* deg       = (int*)(W + 38474752);                    // 200,000 B
    int* rowstart  = (int*)(W + 38674752);                    // 200,016 B
    int* writeptr  = (int*)(W + 38874768);                    // 200,000 B
    int* srcSorted = (int*)(W + 39074768);                    // 3,200,000 B
    int* blockSums = (int*)(W + 42274768);                    // 784 B
    int* blockOff  = (int*)(W + 42275552);                    // 784 B

    unsigned short* wl1b = wb;
    unsigned short* wr1b = wb + 16384;
    unsigned short* wl2b = wb + 32768;
    unsigned short* wr2b = wb + 34816;

    // zero bnsum+bnsq+deg (contiguous)
    hipMemsetAsync(bnsum, 0, (size_t)(1024 + 200000), stream);

    pack_kernel<<<25145, 256, 0, stream>>>(x, Wl1, Wr1, Wl2, Wr2, xb, wb);

    deg_kernel<<<EEDGES / 256, 256, 0, stream>>>(dst, deg);
    blocksum_kernel<<<NB, 256, 0, stream>>>(deg, blockSums);
    scanblocks_kernel<<<1, 256, 0, stream>>>(blockSums, blockOff);
    blockscan_kernel<<<NB, 256, 0, stream>>>(deg, blockOff, rowstart, writeptr);
    bucket_kernel<<<EEDGES / 256, 256, 0, stream>>>(src, dst, writeptr, srcSorted);

    // layer 1
    gather_bf16<<<NNODES / 4, 256, 0, stream>>>(xb, rowstart, srcSorted, aggb);
    lin1_mfma<<<(NNODES + 63) / 64, 256, 0, stream>>>(aggb, xb, wl1b, wr1b, bl1, hb);
    bn_reduce_kernel<<<512, 256, 0, stream>>>(hb, bnsum, bnsq, (NNODES + 511) / 512);
    bn_apply_kernel<<<(NNODES * FH) / 256, 256, 0, stream>>>(hb, x, gamma, beta, a, bnsum, bnsq);

    // layer 2
    gather_bf16<<<NNODES / 4, 256, 0, stream>>>(hb, rowstart, srcSorted, aggb);
    lin2_mfma<<<(NNODES + 63) / 64, 256, 0, stream>>>(aggb, hb, wl2b, wr2b, bl2, out);
}